// Round 9
// baseline (681.566 us; speedup 1.0000x reference)
//
#include <hip/hip_runtime.h>
#include <cstddef>
#include <math.h>

// Problem constants (from reference)
#define BATCH 128
#define DIN   2048
#define NN    2048
#define TT    50
#define MM    (BATCH * TT)   // 6400, m = b*50 + t
#define BN_EPS 1e-4
#define NDIG  4              // 4 digits, pairs i+j<=3 (10)

typedef double double4_t __attribute__((ext_vector_type(4)));
typedef int    int4v    __attribute__((ext_vector_type(4)));
typedef int    int16v   __attribute__((ext_vector_type(16)));

// XOR bank swizzle for the fp64 fallback GEMM
#define SWZ(x) (((x) & 7) << 2)

// ===========================================================================
// TIER 1: exact-enough int8-Ozaki GEMM (4 digits, 10 pairs, int32-exact).
//
// R9 changes (fixes R8's latency exposure; keeps its occupancy + layout):
//  * R8 diagnosis: 1-chunk prefetch + __syncthreads (vmcnt(0) drain) left a
//    366-cy compute window vs 600-900 cy A-load latency -> 75% stall
//    (MfmaUtil 24.9, all pipes idle).  R9: counted-vmcnt pipeline with raw
//    s_barrier (T4; R1 precedent for correctness):
//      A: 3 buffers, staged 2 chunks ahead (window ~732 cy >= HBM lat)
//      B: 2 buffers, staged 1 ahead (L2-resident, ~200 cy)
//    Per chunk: issue B(q+1), A(q+2) -> frags -> 10 MFMAs ->
//    s_waitcnt vmcnt(2) (A(q+2) stays in flight ACROSS the barrier) ->
//    s_barrier.  FIFO: outstanding = A(q+1)x2,B(q+1)x2,A(q+2)x2; vmcnt(2)
//    drains exactly the 4 needed.  WAR-safe: any buffer rewritten by
//    chunk-q issues was last read in chunk q-1, behind a barrier.
//    Buffer periods lcm(3,2)=6 -> unroll 6 (compile-time LDS indices);
//    tail chunks 60..63 explicit (vmcnt 2,2,0,0).
//  * LDS 40 KB -> 4 blocks/CU exactly (160 KB).
// Kept from R8 (counter-verified): mfma_i32_32x32x32_i8 chunk engine,
// lane-ordered linear staging (conflicts 0), linear digit planes, fixed
// A scale sA=64, 8-way split_a, f32 PSP, one-pass stats, XCD-aware grid.
// ===========================================================================

__device__ __forceinline__ void gload16(const void* g, void* l) {
    __builtin_amdgcn_global_load_lds(
        (const __attribute__((address_space(1))) void*)g,
        (__attribute__((address_space(3))) void*)l, 16, 0, 0);
}

// --- split A: X -> Adig[4][M][K] (linear), fixed scale 64 -----------------
// grid (BATCH, 8): each block handles a 256-wide k-slice of one batch row.
__global__ __launch_bounds__(256) void split_a_kernel(
    const float* __restrict__ X,
    signed char* __restrict__ Adig)
{
    __shared__ float Xs[64 * TT];     // 64k x 50t tile

    const int b  = blockIdx.x;
    const int gy = blockIdx.y;        // 8-way K split (each block: 256 k's)
    const int tid = threadIdx.x;
    const float* Xb = X + (size_t)b * (DIN * TT);

    for (int k0 = gy * (DIN / 8); k0 < (gy + 1) * (DIN / 8); k0 += 64) {
        for (int idx = tid; idx < 64 * TT; idx += 256)
            Xs[idx] = Xb[k0 * TT + idx];      // flat-coalesced
        __syncthreads();
        const int kl = tid & 63;
        for (int t = (tid >> 6); t < TT; t += 4) {
            float r = Xs[kl * TT + t] * 64.f;   // fixed sA = 2^6
            const size_t mrow = (size_t)b * TT + t;
            signed char d[NDIG];
#pragma unroll
            for (int i = 0; i < NDIG; ++i) {
                float di = rintf(r);
                r = (r - di) * 128.f;         // exact in fp32
                d[i] = (signed char)(int)di;  // |di| <= 64
            }
#pragma unroll
            for (int i = 0; i < NDIG; ++i)
                Adig[((size_t)i * MM + mrow) * DIN + k0 + kl] = d[i];
        }
        __syncthreads();
    }
}

// --- split B: W[N][K] -> Bdig[4][N][K] (linear) + invB[N] ------------------
__global__ __launch_bounds__(256) void split_b_kernel(
    const float* __restrict__ W,
    signed char* __restrict__ Bdig,
    double* __restrict__ invB)
{
    __shared__ float red[256];
    __shared__ float sBsh;
    const int tid = threadIdx.x;
    for (int rep = 0; rep < 4; ++rep) {
        const int n = blockIdx.x * 4 + rep;
        const float* Wr = W + (size_t)n * DIN;
        float m_loc = 0.f;
        for (int k = tid; k < DIN; k += 256)
            m_loc = fmaxf(m_loc, fabsf(Wr[k]));
        red[tid] = m_loc;
        __syncthreads();
        for (int s = 128; s > 0; s >>= 1) {
            if (tid < s) red[tid] = fmaxf(red[tid], red[tid + s]);
            __syncthreads();
        }
        if (tid == 0) {
            float m = (red[0] == 0.f) ? 1.f : red[0];
            int ex; frexpf(m, &ex);
            sBsh = exp2f((float)(6 - ex));
            invB[n] = ldexp(1.0, ex - 6);
        }
        __syncthreads();
        const float sB = sBsh;
        for (int k = tid; k < DIN; k += 256) {
            float r = Wr[k] * sB;
#pragma unroll
            for (int i = 0; i < NDIG; ++i) {
                float di = rintf(r);
                r = (r - di) * 128.f;
                Bdig[((size_t)i * NN + n) * DIN + k] = (signed char)(int)di;
            }
        }
        __syncthreads();
    }
}

// --- i8 GEMM: 64x64 tile, 4 waves (each 32x32 via 32x32x32 MFMA), ----------
// K-chunk 32, A 3-buf (2-ahead) + B 2-buf (1-ahead), counted vmcnt + raw
// s_barrier (loads stay in flight across barriers), 40 KB LDS, 4 blocks/CU.
#define MFMA32(AI, BJ, W) \
    acc[W] = __builtin_amdgcn_mfma_i32_32x32x32_i8(a[AI], b[BJ], acc[W], 0, 0, 0)

// one K-chunk; AB/BB/NBB/NAB/VMN are compile-time literals.
#define CHUNK(AB, BB, Q, ISSB, NBB, ISSA, NAB, VMN)                        \
    {                                                                      \
        if (ISSB) stageB(NBB, ((Q) + 1) << 5);                             \
        if (ISSA) stageA(NAB, ((Q) + 2) << 5);                             \
        __builtin_amdgcn_sched_barrier(0);                                 \
        int4v a[NDIG], b[NDIG];                                            \
        _Pragma("unroll")                                                  \
        for (int p = 0; p < NDIG; ++p) {                                   \
            a[p] = *(const int4v*)&Asd[AB][p][amh][lane << 4];             \
            b[p] = *(const int4v*)&Bsd[BB][p][bnh][lane << 4];             \
        }                                                                  \
        __builtin_amdgcn_s_setprio(1);                                     \
        MFMA32(0, 0, 0);                                                   \
        MFMA32(0, 1, 1); MFMA32(1, 0, 1);                                  \
        MFMA32(0, 2, 2); MFMA32(1, 1, 2); MFMA32(2, 0, 2);                 \
        MFMA32(0, 3, 3); MFMA32(1, 2, 3); MFMA32(2, 1, 3); MFMA32(3, 0, 3);\
        __builtin_amdgcn_s_setprio(0);                                     \
        asm volatile("s_waitcnt vmcnt(" #VMN ")" ::: "memory");            \
        __builtin_amdgcn_sched_barrier(0);                                 \
        __builtin_amdgcn_s_barrier();                                      \
        __builtin_amdgcn_sched_barrier(0);                                 \
    }

__global__ __launch_bounds__(256, 4) void gemm_i8_kernel(
    const signed char* __restrict__ Adig,   // [4][MM][DIN] linear
    const signed char* __restrict__ Bdig,   // [4][NN][DIN] linear
    const double* __restrict__ invB,        // [NN]
    float* __restrict__ PSP)                // [MM][NN] (f32)
{
    // [buf][digit][m/n-half][lane-ordered 1KB: (ksub=l>>5)*512 + (l&31)*16]
    __shared__ __align__(16) signed char Asd[3][NDIG][2][1024];  // 24 KB
    __shared__ __align__(16) signed char Bsd[2][NDIG][2][1024];  // 16 KB

    const int tid  = threadIdx.x;
    const int lane = tid & 63;
    const int wv   = tid >> 6;

    // XCD-aware decomposition: xcd = bid&7 owns 4 n-strips (B L2-resident),
    // streams all 100 m-panels; 4 consecutive blocks share one A panel.
    const int orig  = blockIdx.x;            // 0..3199
    const int local = orig >> 3;             // 0..399
    const int n0 = (((orig & 7) << 2) + (local & 3)) << 6;
    const int m0 = (local >> 2) << 6;

    // staging: wave wv stages digit wv. Per-lane GLOBAL src so the linear
    // LDS image is exactly fragment order: lane l <-> (ksub=l>>5, row=l&31).
    const int r32 = lane & 31;
    const int ks  = lane >> 5;
    const signed char* aS0 = Adig + ((size_t)wv * MM + m0 +      r32) * DIN + ks * 16;
    const signed char* aS1 = Adig + ((size_t)wv * MM + m0 + 32 + r32) * DIN + ks * 16;
    const signed char* bS0 = Bdig + ((size_t)wv * NN + n0 +      r32) * DIN + ks * 16;
    const signed char* bS1 = Bdig + ((size_t)wv * NN + n0 + 32 + r32) * DIN + ks * 16;

    auto stageA = [&](int buf, int k0) {
        gload16(aS0 + k0, &Asd[buf][wv][0][0]);
        gload16(aS1 + k0, &Asd[buf][wv][1][0]);
    };
    auto stageB = [&](int buf, int k0) {
        gload16(bS0 + k0, &Bsd[buf][wv][0][0]);
        gload16(bS1 + k0, &Bsd[buf][wv][1][0]);
    };

    const int wm  = (wv >> 1) << 5;          // wave's m-offset in tile
    const int wn  = (wv & 1) << 5;           // wave's n-offset in tile
    const int amh = wv >> 1;                 // A m-half this wave consumes
    const int bnh = wv & 1;                  // B n-half this wave consumes

    int16v acc[NDIG];
#pragma unroll
    for (int w = 0; w < NDIG; ++w)
#pragma unroll
        for (int e = 0; e < 16; ++e) acc[w][e] = 0;

    // prologue: A(0)->buf0, B(0)->buf0, A(1)->buf1; wait A(0),B(0) only
    // (per-wave FIFO: vmcnt(2) leaves A(1)'s 2 loads in flight).
    stageA(0, 0);
    stageB(0, 0);
    stageA(1, 32);
    asm volatile("s_waitcnt vmcnt(2)" ::: "memory");
    __builtin_amdgcn_sched_barrier(0);
    __builtin_amdgcn_s_barrier();
    __builtin_amdgcn_sched_barrier(0);

    // chunk q: AB=q%3, BB=q%2; issues B(q+1)->(q+1)%2, A(q+2)->(q+2)%3.
    // NIT = 64: main loop q=0..59 (period-6 unroll), tail 60..63.
    for (int q = 0; q < 60; q += 6) {
        CHUNK(0, 0, q + 0, true, 1, true, 2, 2);
        CHUNK(1, 1, q + 1, true, 0, true, 0, 2);
        CHUNK(2, 0, q + 2, true, 1, true, 1, 2);
        CHUNK(0, 1, q + 3, true, 0, true, 2, 2);
        CHUNK(1, 0, q + 4, true, 1, true, 0, 2);
        CHUNK(2, 1, q + 5, true, 0, true, 1, 2);
    }
    CHUNK(0, 0, 60, true, 1, true, 2, 2);
    CHUNK(1, 1, 61, true, 0, true, 0, 2);
    CHUNK(2, 0, 62, true, 1, false, 0, 0);
    CHUNK(0, 1, 63, false, 0, false, 0, 0);

    // epilogue: D layout col=lane&31, row=(reg&3)+8*(reg>>2)+4*(lane>>5)
    const double c1 = 1.0 / 128.0, c2 = c1 * c1, c3 = c2 * c1;
    const double invA = 1.0 / 64.0;          // fixed A scale
    const int ncol = n0 + wn + (lane & 31);
    const double ib = invA * invB[ncol];
    const int rbase = m0 + wm + 4 * (lane >> 5);
#pragma unroll
    for (int reg = 0; reg < 16; ++reg) {
        const int mrow = rbase + (reg & 3) + 8 * (reg >> 2);
        double s = (double)acc[0][reg]
                 + c1 * (double)acc[1][reg]
                 + c2 * (double)acc[2][reg]
                 + c3 * (double)acc[3][reg];
        PSP[(size_t)mrow * NN + ncol] = (float)(s * ib);
    }
}

// ===========================================================================
// TIER 2 fallback: fp64-MFMA GEMM (round-8, proven 1039 us total)
// ===========================================================================
#define BKK 32

template <typename PT>
__global__ __launch_bounds__(256, 5) void gemm_psp_kernel(
    const float* __restrict__ X,
    const float* __restrict__ W,
    PT* __restrict__ PSP)
{
    __shared__ float As[2][BKK][64];
    __shared__ float Bs[2][64][BKK];

    const int tid = threadIdx.x;
    const int m0 = blockIdx.y * 64;
    const int n0 = blockIdx.x * 64;

    const int a_m = tid & 63;
    const int a_k = tid >> 6;
    const int m_g = m0 + a_m;
    const int ab  = m_g / TT;
    const int at  = m_g - ab * TT;
    const float* Aptr = X + (size_t)ab * (DIN * TT) + at;

    const int b_n = tid >> 2;
    const int b_k = (tid & 3) * 8;
    const float* Wptr = W + (size_t)(n0 + b_n) * DIN + b_k;
    const int bswz_st = SWZ(b_n);

    const int lane = tid & 63;
    const int wv   = tid >> 6;
    const int wm   = (wv >> 1) * 32;
    const int wn   = (wv & 1) * 32;
    const int row  = lane & 15;
    const int grp  = lane >> 4;
    const int bswz_rd = SWZ(row);

    double4_t acc[2][2];
#pragma unroll
    for (int i = 0; i < 2; ++i)
#pragma unroll
        for (int j = 0; j < 2; ++j) acc[i][j] = double4_t{0.0, 0.0, 0.0, 0.0};

    {
#pragma unroll
        for (int j = 0; j < 8; ++j) {
            const int kr = a_k + 4 * j;
            As[0][kr][a_m ^ SWZ(kr)] = Aptr[kr * TT];
        }
        *(float4*)&Bs[0][b_n][(b_k + 0) ^ bswz_st] = *(const float4*)(Wptr);
        *(float4*)&Bs[0][b_n][(b_k + 4) ^ bswz_st] = *(const float4*)(Wptr + 4);
    }

    const int NIT = DIN / BKK;
    for (int it = 0; it < NIT; ++it) {
        const int buf = it & 1;
        __syncthreads();

        float a_nxt[8];
        float4 b_nxt0, b_nxt1;
        if (it + 1 < NIT) {
            const int k0n = (it + 1) * BKK;
#pragma unroll
            for (int j = 0; j < 8; ++j)
                a_nxt[j] = Aptr[(k0n + a_k + 4 * j) * TT];
            b_nxt0 = *(const float4*)(Wptr + k0n);
            b_nxt1 = *(const float4*)(Wptr + k0n + 4);
        }

#pragma unroll
        for (int kq = 0; kq < BKK; kq += 4) {
            const int kr = kq + grp;
            const int aswz = SWZ(kr);
            const double a0 = (double)As[buf][kr][(wm + row) ^ aswz];
            const double a1 = (double)As[buf][kr][(wm + row + 16) ^ aswz];
            const double b0 = (double)Bs[buf][wn + row][kr ^ bswz_rd];
            const double b1 = (double)Bs[buf][wn + row + 16][kr ^ bswz_rd];
            acc[0][0] = __builtin_amdgcn_mfma_f64_16x16x4f64(a0, b0, acc[0][0], 0, 0, 0);
            acc[0][1] = __builtin_amdgcn_mfma_f64_16x16x4f64(a0, b1, acc[0][1], 0, 0, 0);
            acc[1][0] = __builtin_amdgcn_mfma_f64_16x16x4f64(a1, b0, acc[1][0], 0, 0, 0);
            acc[1][1] = __builtin_amdgcn_mfma_f64_16x16x4f64(a1, b1, acc[1][1], 0, 0, 0);
        }

        if (it + 1 < NIT) {
            const int nb = 1 - buf;
#pragma unroll
            for (int j = 0; j < 8; ++j) {
                const int kr = a_k + 4 * j;
                As[nb][kr][a_m ^ SWZ(kr)] = a_nxt[j];
            }
            *(float4*)&Bs[nb][b_n][(b_k + 0) ^ bswz_st] = b_nxt0;
            *(float4*)&Bs[nb][b_n][(b_k + 4) ^ bswz_st] = b_nxt1;
        }
    }

#pragma unroll
    for (int i = 0; i < 2; ++i)
#pragma unroll
        for (int j = 0; j < 2; ++j)
#pragma unroll
            for (int r = 0; r < 4; ++r) {
                const int mrow = m0 + wm + 16 * i + grp + 4 * r;   // f64 H2 layout
                PSP[(size_t)mrow * NN + (n0 + wn + 16 * j + row)] = (PT)acc[i][j][r];
            }
}

// ---------------------------------------------------------------------------
// BN stats + LIF recurrence (shared by all tiers)
// ---------------------------------------------------------------------------
template <typename PT>
__global__ __launch_bounds__(256) void stats_kernel(
    const PT* __restrict__ PSP, const float* __restrict__ bias,
    double* __restrict__ mean_out, double* __restrict__ invstd_out)
{
    const int t = blockIdx.x >> 3;
    const int n = ((blockIdx.x & 7) << 8) + threadIdx.x;
    const double bb = (double)bias[n];
    const PT* p = PSP + (size_t)t * NN + n;

    // one-pass sum + sumsq (var = E[x^2]-E[x]^2, exact to ~1e-15 in double)
    double s = 0.0, ss = 0.0;
#pragma unroll 8
    for (int b = 0; b < BATCH; ++b) {
        const double v = (double)p[(size_t)b * (TT * NN)];
        s += v; ss += v * v;
    }
    const double mu0 = s * (1.0 / BATCH);
    const double var = fmax(ss * (1.0 / BATCH) - mu0 * mu0, 0.0);
    mean_out[t * NN + n]   = mu0 + bb;
    invstd_out[t * NN + n] = 1.0 / sqrt(var + BN_EPS);
}

template <typename PT>
__global__ __launch_bounds__(256) void recur_kernel(
    const PT* __restrict__ PSP, const float* __restrict__ bias,
    const double* __restrict__ mean_arr, const double* __restrict__ invstd_arr,
    const float* __restrict__ gamma, const float* __restrict__ decay_v,
    const float* __restrict__ reset_decay, const float* __restrict__ reset_v,
    float* __restrict__ out)
{
    __shared__ float spk[256 * (TT + 1)];

    const int b  = blockIdx.x >> 3;
    const int nc = blockIdx.x & 7;
    const int n  = (nc << 8) + threadIdx.x;
    const int tid = threadIdx.x;

    const double dv = (double)decay_v[n];
    const double rd = (double)reset_decay[n];
    const double rv = (double)reset_v[n];
    const double bb = (double)bias[n];

    double v = 0.0, r = 0.0;
    const PT* p = PSP + (size_t)b * (TT * NN) + n;
    const float* ga = gamma + n;
    const double* me = mean_arr + n;
    const double* is = invstd_arr + n;

    for (int t = 0; t < TT; ++t) {
        const double psp = (double)p[t * NN] + bb;
        const double bn  = (double)ga[t * NN] * (psp - me[t * NN]) * is[t * NN];
        v = v * dv + bn - r;
        const double s = (v > 1.0) ? 1.0 : 0.0;
        r = r * rd + s * rv;
        spk[tid * (TT + 1) + t] = (float)s;
    }
    __syncthreads();

    const size_t base = (size_t)b * (NN * TT) + (size_t)nc * (256 * TT);
    for (int i = tid; i < 256 * TT; i += 256) {
        const int n_l = i / TT;
        out[base + i] = spk[n_l * (TT + 1) + (i - n_l * TT)];
    }

    const size_t fin = (size_t)BATCH * NN * TT;
    out[fin + (size_t)b * NN + n]                      = (float)v;
    out[fin + (size_t)BATCH * NN + (size_t)b * NN + n] = (float)r;
}

// ---------------------------------------------------------------------------
template <typename PT>
static void launch_fp64(const float* X, const float* W, const float* bias,
                        const float* gamma, const float* decay_v,
                        const float* reset_dec, const float* reset_v,
                        float* out, void* d_ws, hipStream_t stream)
{
    PT* PSP = (PT*)d_ws;
    char* after = (char*)d_ws + (size_t)MM * NN * sizeof(PT);
    double* meanA  = (double*)after;
    double* invstd = meanA + (size_t)TT * NN;

    dim3 ggrid(NN / 64, MM / 64);
    gemm_psp_kernel<PT><<<ggrid, 256, 0, stream>>>(X, W, PSP);
    stats_kernel<PT><<<TT * (NN / 256), 256, 0, stream>>>(PSP, bias, meanA, invstd);
    recur_kernel<PT><<<BATCH * (NN / 256), 256, 0, stream>>>(
        PSP, bias, meanA, invstd, gamma, decay_v, reset_dec, reset_v, out);
}

extern "C" void kernel_launch(void* const* d_in, const int* in_sizes, int n_in,
                              void* d_out, int out_size, void* d_ws, size_t ws_size,
                              hipStream_t stream) {
    (void)in_sizes; (void)n_in; (void)out_size;
    const float* X          = (const float*)d_in[0];
    const float* W          = (const float*)d_in[1];
    const float* bias       = (const float*)d_in[2];
    const float* gamma      = (const float*)d_in[3];
    const float* decay_v    = (const float*)d_in[4];
    const float* reset_dec  = (const float*)d_in[5];
    const float* reset_v    = (const float*)d_in[6];
    float* out = (float*)d_out;

    const size_t psp_f   = (size_t)MM * NN * sizeof(float);    // 52.43 MB
    const size_t psp_d   = (size_t)MM * NN * sizeof(double);   // 104.86 MB
    const size_t stats_b = (size_t)TT * NN * 2 * sizeof(double);
    const size_t adig_b  = (size_t)NDIG * MM * DIN;            // 52.43 MB
    const size_t bdig_b  = (size_t)NDIG * NN * DIN;            // 16.78 MB
    const size_t need_i8 = psp_f + stats_b + adig_b + bdig_b + NN * sizeof(double);
    const size_t need_d  = psp_d + stats_b;

    if (ws_size >= need_i8) {
        float*  PSP    = (float*)d_ws;
        char*   cur    = (char*)d_ws + psp_f;
        double* meanA  = (double*)cur;              cur += (size_t)TT * NN * 8;
        double* invstd = (double*)cur;              cur += (size_t)TT * NN * 8;
        signed char* Adig = (signed char*)cur;      cur += adig_b;
        signed char* Bdig = (signed char*)cur;      cur += bdig_b;
        double* invB   = (double*)cur;

        split_a_kernel<<<dim3(BATCH, 8), 256, 0, stream>>>(X, Adig);
        split_b_kernel<<<NN / 4, 256, 0, stream>>>(W, Bdig, invB);
        gemm_i8_kernel<<<dim3((MM / 64) * (NN / 64)), 256, 0, stream>>>(
            Adig, Bdig, invB, PSP);
        stats_kernel<float><<<TT * (NN / 256), 256, 0, stream>>>(PSP, bias, meanA, invstd);
        recur_kernel<float><<<BATCH * (NN / 256), 256, 0, stream>>>(
            PSP, bias, meanA, invstd, gamma, decay_v, reset_dec, reset_v, out);
    } else if (ws_size >= need_d) {
        launch_fp64<double>(X, W, bias, gamma, decay_v, reset_dec, reset_v, out, d_ws, stream);
    } else {
        launch_fp64<float>(X, W, bias, gamma, decay_v, reset_dec, reset_v, out, d_ws, stream);
    }
}

// Round 10
// 480.509 us; speedup vs baseline: 1.4184x; 1.4184x over previous
//
#include <hip/hip_runtime.h>
#include <cstddef>
#include <math.h>

// Problem constants (from reference)
#define BATCH 128
#define DIN   2048
#define NN    2048
#define TT    50
#define MM    (BATCH * TT)   // 6400, m = b*50 + t
#define BN_EPS 1e-4
#define NDIG  4              // 4 digits, pairs i+j<=3 (10)

typedef double double4_t __attribute__((ext_vector_type(4)));
typedef int    int4v    __attribute__((ext_vector_type(4)));
typedef int    int16v   __attribute__((ext_vector_type(16)));

// XOR bank swizzle for the fp64 fallback GEMM
#define SWZ(x) (((x) & 7) << 2)

// ===========================================================================
// TIER 1: exact-enough int8-Ozaki GEMM (4 digits, 10 pairs, int32-exact).
//
// R10 changes (fixes R8/R9's root causes, revealed by counters):
//  * R8/R9 lane-ordered staging was UNCOALESCED (each lane 16B from a row
//    2KB away -> 64 scattered lines/instr; FETCH 286->315->425 MB) and R9
//    additionally spilled (WRITE 51->167 MB scratch signature).
//  * Fix: digit planes stored PRE-TILED in fragment order:
//    [p][panel=mp][kchunk=kc] 1KB blocks, internal order (ksub,row,16B) =
//    exactly lane*16 MFMA fragment order.  global_load_lds now reads 1KB
//    CONTIGUOUS per instruction (coalesced) AND the LDS image is
//    fragment-ordered (conflict-free ds_read_b128 by construction).
//  * Geometry: block 128x64, wave = 32x64 (own A panel, both B halves):
//    24 ds_read_b128 per 40 MFMAs = 0.6 KB/MFMA (R7: 0.8) -> LDS pipe
//    (1125 cy/block-tile x2) finally below MFMA pipe (2928 cy/SIMD).
//    LDS 80 KB (A dbuf 64 + B single 16) -> 2 blocks/CU; the 2 waves/SIMD
//    come from INDEPENDENT blocks (decorrelated barriers).
//  * Sync = R7's proven skeleton only: plain __syncthreads, stage mid-tile,
//    NO counted vmcnt.  b1 frags read after the nh0 MFMA cluster to cap
//    liveness (~220 unified regs, fits 2 waves/SIMD; launch_bounds(256,2)).
// Kept (counter-verified): mfma_i32_32x32x32_i8 (layouts HW-validated by
// R8/R9 passing), fixed A scale sA=64, 8-way split_a, f32 PSP, one-pass
// stats, XCD-aware grid (1600 blocks, %8==0).
// ===========================================================================

__device__ __forceinline__ void gload16(const void* g, void* l) {
    __builtin_amdgcn_global_load_lds(
        (const __attribute__((address_space(1))) void*)g,
        (__attribute__((address_space(3))) void*)l, 16, 0, 0);
}

// --- split A: X -> Adig tiled [p][mp][kc][ksub][row][16], scale 64 --------
// grid (BATCH, 8): each block handles a 256-wide k-slice of one batch row.
__global__ __launch_bounds__(256) void split_a_kernel(
    const float* __restrict__ X,
    signed char* __restrict__ Adig)
{
    __shared__ float Xs[64 * TT];     // 64k x 50t tile

    const int b  = blockIdx.x;
    const int gy = blockIdx.y;        // 8-way K split (each block: 256 k's)
    const int tid = threadIdx.x;
    const float* Xb = X + (size_t)b * (DIN * TT);

    for (int k0 = gy * (DIN / 8); k0 < (gy + 1) * (DIN / 8); k0 += 64) {
        for (int idx = tid; idx < 64 * TT; idx += 256)
            Xs[idx] = Xb[k0 * TT + idx];      // flat-coalesced
        __syncthreads();
        const int kl   = tid & 63;
        const int kcl  = (k0 + kl) >> 5;           // global 32-k chunk
        const int sub  = ((kl >> 4) & 1) << 9;     // ksub*512
        const int byte = kl & 15;
        for (int t = (tid >> 6); t < TT; t += 4) {
            float r = Xs[kl * TT + t] * 64.f;   // fixed sA = 2^6
            const int mrow = b * TT + t;
            const int mp  = mrow >> 5;
            const int row = mrow & 31;
            signed char d[NDIG];
#pragma unroll
            for (int i = 0; i < NDIG; ++i) {
                float di = rintf(r);
                r = (r - di) * 128.f;         // exact in fp32
                d[i] = (signed char)(int)di;  // |di| <= 64
            }
#pragma unroll
            for (int i = 0; i < NDIG; ++i)
                Adig[((((size_t)i * (MM / 32) + mp) * (DIN / 32) + kcl) << 10)
                     + sub + (row << 4) + byte] = d[i];
        }
        __syncthreads();
    }
}

// --- split B: W -> Bdig tiled [p][np][kc][ksub][row][16] + invB[N] ---------
__global__ __launch_bounds__(256) void split_b_kernel(
    const float* __restrict__ W,
    signed char* __restrict__ Bdig,
    double* __restrict__ invB)
{
    __shared__ float red[256];
    __shared__ float sBsh;
    const int tid = threadIdx.x;
    for (int rep = 0; rep < 4; ++rep) {
        const int n = blockIdx.x * 4 + rep;
        const float* Wr = W + (size_t)n * DIN;
        float m_loc = 0.f;
        for (int k = tid; k < DIN; k += 256)
            m_loc = fmaxf(m_loc, fabsf(Wr[k]));
        red[tid] = m_loc;
        __syncthreads();
        for (int s = 128; s > 0; s >>= 1) {
            if (tid < s) red[tid] = fmaxf(red[tid], red[tid + s]);
            __syncthreads();
        }
        if (tid == 0) {
            float m = (red[0] == 0.f) ? 1.f : red[0];
            int ex; frexpf(m, &ex);
            sBsh = exp2f((float)(6 - ex));
            invB[n] = ldexp(1.0, ex - 6);
        }
        __syncthreads();
        const float sB = sBsh;
        const int np   = n >> 5;
        const int rowb = (n & 31) << 4;
        for (int k = tid; k < DIN; k += 256) {
            float r = Wr[k] * sB;
            const int kc  = k >> 5;
            const int sub = ((k >> 4) & 1) << 9;
            const int byte = k & 15;
#pragma unroll
            for (int i = 0; i < NDIG; ++i) {
                float di = rintf(r);
                r = (r - di) * 128.f;
                Bdig[((((size_t)i * (NN / 32) + np) * (DIN / 32) + kc) << 10)
                     + sub + rowb + byte] = (signed char)(int)di;
            }
        }
        __syncthreads();
    }
}

// --- i8 GEMM: 128x64 block tile, 4 waves (each 32x64), K-tile 64 -----------
// A dbuf (64 KB) + B single-buf (16 KB) = 80 KB, 2 blocks/CU.
#define PAIRS(NH, BARR)                                                    \
    __builtin_amdgcn_s_setprio(1);                                         \
    _Pragma("unroll")                                                      \
    for (int kc = 0; kc < 2; ++kc)                                         \
        _Pragma("unroll")                                                  \
        for (int i = 0; i < NDIG; ++i)                                     \
            _Pragma("unroll")                                              \
            for (int j = 0; j + i < NDIG; ++j)                             \
                acc[NH][i + j] = __builtin_amdgcn_mfma_i32_32x32x32_i8(    \
                    a[kc][i], BARR[kc][j], acc[NH][i + j], 0, 0, 0);       \
    __builtin_amdgcn_s_setprio(0);

// one K-tile; BUF is a literal 0/1.  Reads of Bsd all precede the mid
// barrier; restage (after it) overwrites safely.  End __syncthreads drains
// vmcnt(0) -> next tile staged.  b1 read after nh0 cluster caps liveness.
#define TILE(BUF, IT)                                                      \
    {                                                                      \
        int4v a[2][NDIG], bb[2][NDIG];                                     \
        _Pragma("unroll")                                                  \
        for (int c = 0; c < 2; ++c)                                        \
            _Pragma("unroll")                                              \
            for (int p = 0; p < NDIG; ++p) {                               \
                a[c][p]  = *(const int4v*)&Asd[BUF][p][wv][c][lane << 4];  \
                bb[c][p] = *(const int4v*)&Bsd[p][0][c][lane << 4];        \
            }                                                              \
        PAIRS(0, bb)                                                       \
        _Pragma("unroll")                                                  \
        for (int c = 0; c < 2; ++c)                                        \
            _Pragma("unroll")                                              \
            for (int p = 0; p < NDIG; ++p)                                 \
                bb[c][p] = *(const int4v*)&Bsd[p][1][c][lane << 4];        \
        __syncthreads();                                                   \
        if ((IT) + 1 < NIT) { stageA((BUF) ^ 1, (IT) + 1); stageB((IT) + 1); } \
        __builtin_amdgcn_sched_barrier(0);                                 \
        PAIRS(1, bb)                                                       \
        __syncthreads();                                                   \
    }

__global__ __launch_bounds__(256, 2) void gemm_i8_kernel(
    const signed char* __restrict__ Adig,   // [4][MM/32][DIN/32] 1KB frag blocks
    const signed char* __restrict__ Bdig,   // [4][NN/32][DIN/32] 1KB frag blocks
    const double* __restrict__ invB,        // [NN]
    float* __restrict__ PSP)                // [MM][NN] (f32)
{
    // Asd[buf][digit][panel][kc][1KB], Bsd[digit][nh][kc][1KB]
    __shared__ __align__(16) signed char Asd[2][NDIG][4][2][1024];  // 64 KB
    __shared__ __align__(16) signed char Bsd[NDIG][2][2][1024];     // 16 KB

    const int tid  = threadIdx.x;
    const int lane = tid & 63;
    const int wv   = tid >> 6;

    // XCD-aware decomposition (1600 blocks, %8==0): xcd = bid&7 owns 4
    // n-strips (B 2MB, L2-resident); 4 consecutive blocks share one A panel.
    const int orig  = blockIdx.x;            // 0..1599
    const int local = orig >> 3;             // 0..199
    const int n0 = (((orig & 7) << 2) + (local & 3)) << 6;
    const int m0 = (local >> 2) << 7;        // 128-row panels

    // staging: 1KB contiguous per gload16, lane offset = lane*16 (coalesced;
    // LDS image = fragment order by construction).
    const int mpw = (m0 >> 5) + wv;          // wave's own A 32-row panel
    const int np0 = n0 >> 5;
    const int bnh = wv & 1, bkc = wv >> 1;   // B staging assignment
    const size_t APL = ((size_t)(MM / 32) * (DIN / 32)) << 10;  // digit stride
    const size_t BPL = ((size_t)(NN / 32) * (DIN / 32)) << 10;
    const signed char* Abase =
        Adig + (((size_t)mpw * (DIN / 32)) << 10) + (lane << 4);
    const signed char* Bbase =
        Bdig + (((size_t)(np0 + bnh) * (DIN / 32)) << 10) + (lane << 4);

    auto stageA = [&](int buf, int kt) {
#pragma unroll
        for (int p = 0; p < NDIG; ++p)
#pragma unroll
            for (int c = 0; c < 2; ++c)
                gload16(Abase + (size_t)p * APL + ((size_t)((kt << 1) + c) << 10),
                        &Asd[buf][p][wv][c][0]);
    };
    auto stageB = [&](int kt) {
#pragma unroll
        for (int p = 0; p < NDIG; ++p)
            gload16(Bbase + (size_t)p * BPL + ((size_t)((kt << 1) + bkc) << 10),
                    &Bsd[p][bnh][bkc][0]);
    };

    int16v acc[2][NDIG];
#pragma unroll
    for (int nh = 0; nh < 2; ++nh)
#pragma unroll
        for (int w = 0; w < NDIG; ++w)
#pragma unroll
            for (int e = 0; e < 16; ++e) acc[nh][w][e] = 0;

    // prologue: stage tile 0 (A buf0 + B), drain, go
    stageA(0, 0);
    stageB(0);
    __syncthreads();

    const int NIT = DIN / 64;                // 32, even
    for (int it = 0; it < NIT; it += 2) {
        TILE(0, it);
        TILE(1, it + 1);
    }

    // epilogue: D layout col=lane&31, row=(reg&3)+8*(reg>>2)+4*(lane>>5)
    const double c1 = 1.0 / 128.0, c2 = c1 * c1, c3 = c2 * c1;
    const double invA = 1.0 / 64.0;          // fixed A scale
    const int colr  = lane & 31;
    const int rbase = m0 + (wv << 5) + 4 * (lane >> 5);
#pragma unroll
    for (int nh = 0; nh < 2; ++nh) {
        const int ncol = n0 + (nh << 5) + colr;
        const double ib = invA * invB[ncol];
#pragma unroll
        for (int reg = 0; reg < 16; ++reg) {
            const int mrow = rbase + (reg & 3) + 8 * (reg >> 2);
            double s = (double)acc[nh][0][reg]
                     + c1 * (double)acc[nh][1][reg]
                     + c2 * (double)acc[nh][2][reg]
                     + c3 * (double)acc[nh][3][reg];
            PSP[(size_t)mrow * NN + ncol] = (float)(s * ib);
        }
    }
}

// ===========================================================================
// TIER 2 fallback: fp64-MFMA GEMM (round-8, proven 1039 us total)
// ===========================================================================
#define BKK 32

template <typename PT>
__global__ __launch_bounds__(256, 5) void gemm_psp_kernel(
    const float* __restrict__ X,
    const float* __restrict__ W,
    PT* __restrict__ PSP)
{
    __shared__ float As[2][BKK][64];
    __shared__ float Bs[2][64][BKK];

    const int tid = threadIdx.x;
    const int m0 = blockIdx.y * 64;
    const int n0 = blockIdx.x * 64;

    const int a_m = tid & 63;
    const int a_k = tid >> 6;
    const int m_g = m0 + a_m;
    const int ab  = m_g / TT;
    const int at  = m_g - ab * TT;
    const float* Aptr = X + (size_t)ab * (DIN * TT) + at;

    const int b_n = tid >> 2;
    const int b_k = (tid & 3) * 8;
    const float* Wptr = W + (size_t)(n0 + b_n) * DIN + b_k;
    const int bswz_st = SWZ(b_n);

    const int lane = tid & 63;
    const int wv   = tid >> 6;
    const int wm   = (wv >> 1) * 32;
    const int wn   = (wv & 1) * 32;
    const int row  = lane & 15;
    const int grp  = lane >> 4;
    const int bswz_rd = SWZ(row);

    double4_t acc[2][2];
#pragma unroll
    for (int i = 0; i < 2; ++i)
#pragma unroll
        for (int j = 0; j < 2; ++j) acc[i][j] = double4_t{0.0, 0.0, 0.0, 0.0};

    {
#pragma unroll
        for (int j = 0; j < 8; ++j) {
            const int kr = a_k + 4 * j;
            As[0][kr][a_m ^ SWZ(kr)] = Aptr[kr * TT];
        }
        *(float4*)&Bs[0][b_n][(b_k + 0) ^ bswz_st] = *(const float4*)(Wptr);
        *(float4*)&Bs[0][b_n][(b_k + 4) ^ bswz_st] = *(const float4*)(Wptr + 4);
    }

    const int NIT = DIN / BKK;
    for (int it = 0; it < NIT; ++it) {
        const int buf = it & 1;
        __syncthreads();

        float a_nxt[8];
        float4 b_nxt0, b_nxt1;
        if (it + 1 < NIT) {
            const int k0n = (it + 1) * BKK;
#pragma unroll
            for (int j = 0; j < 8; ++j)
                a_nxt[j] = Aptr[(k0n + a_k + 4 * j) * TT];
            b_nxt0 = *(const float4*)(Wptr + k0n);
            b_nxt1 = *(const float4*)(Wptr + k0n + 4);
        }

#pragma unroll
        for (int kq = 0; kq < BKK; kq += 4) {
            const int kr = kq + grp;
            const int aswz = SWZ(kr);
            const double a0 = (double)As[buf][kr][(wm + row) ^ aswz];
            const double a1 = (double)As[buf][kr][(wm + row + 16) ^ aswz];
            const double b0 = (double)Bs[buf][wn + row][kr ^ bswz_rd];
            const double b1 = (double)Bs[buf][wn + row + 16][kr ^ bswz_rd];
            acc[0][0] = __builtin_amdgcn_mfma_f64_16x16x4f64(a0, b0, acc[0][0], 0, 0, 0);
            acc[0][1] = __builtin_amdgcn_mfma_f64_16x16x4f64(a0, b1, acc[0][1], 0, 0, 0);
            acc[1][0] = __builtin_amdgcn_mfma_f64_16x16x4f64(a1, b0, acc[1][0], 0, 0, 0);
            acc[1][1] = __builtin_amdgcn_mfma_f64_16x16x4f64(a1, b1, acc[1][1], 0, 0, 0);
        }

        if (it + 1 < NIT) {
            const int nb = 1 - buf;
#pragma unroll
            for (int j = 0; j < 8; ++j) {
                const int kr = a_k + 4 * j;
                As[nb][kr][a_m ^ SWZ(kr)] = a_nxt[j];
            }
            *(float4*)&Bs[nb][b_n][(b_k + 0) ^ bswz_st] = b_nxt0;
            *(float4*)&Bs[nb][b_n][(b_k + 4) ^ bswz_st] = b_nxt1;
        }
    }

#pragma unroll
    for (int i = 0; i < 2; ++i)
#pragma unroll
        for (int j = 0; j < 2; ++j)
#pragma unroll
            for (int r = 0; r < 4; ++r) {
                const int mrow = m0 + wm + 16 * i + grp + 4 * r;   // f64 H2 layout
                PSP[(size_t)mrow * NN + (n0 + wn + 16 * j + row)] = (PT)acc[i][j][r];
            }
}

// ---------------------------------------------------------------------------
// BN stats + LIF recurrence (shared by all tiers)
// ---------------------------------------------------------------------------
template <typename PT>
__global__ __launch_bounds__(256) void stats_kernel(
    const PT* __restrict__ PSP, const float* __restrict__ bias,
    double* __restrict__ mean_out, double* __restrict__ invstd_out)
{
    const int t = blockIdx.x >> 3;
    const int n = ((blockIdx.x & 7) << 8) + threadIdx.x;
    const double bb = (double)bias[n];
    const PT* p = PSP + (size_t)t * NN + n;

    // one-pass sum + sumsq (var = E[x^2]-E[x]^2, exact to ~1e-15 in double)
    double s = 0.0, ss = 0.0;
#pragma unroll 8
    for (int b = 0; b < BATCH; ++b) {
        const double v = (double)p[(size_t)b * (TT * NN)];
        s += v; ss += v * v;
    }
    const double mu0 = s * (1.0 / BATCH);
    const double var = fmax(ss * (1.0 / BATCH) - mu0 * mu0, 0.0);
    mean_out[t * NN + n]   = mu0 + bb;
    invstd_out[t * NN + n] = 1.0 / sqrt(var + BN_EPS);
}

template <typename PT>
__global__ __launch_bounds__(256) void recur_kernel(
    const PT* __restrict__ PSP, const float* __restrict__ bias,
    const double* __restrict__ mean_arr, const double* __restrict__ invstd_arr,
    const float* __restrict__ gamma, const float* __restrict__ decay_v,
    const float* __restrict__ reset_decay, const float* __restrict__ reset_v,
    float* __restrict__ out)
{
    __shared__ float spk[256 * (TT + 1)];

    const int b  = blockIdx.x >> 3;
    const int nc = blockIdx.x & 7;
    const int n  = (nc << 8) + threadIdx.x;
    const int tid = threadIdx.x;

    const double dv = (double)decay_v[n];
    const double rd = (double)reset_decay[n];
    const double rv = (double)reset_v[n];
    const double bb = (double)bias[n];

    double v = 0.0, r = 0.0;
    const PT* p = PSP + (size_t)b * (TT * NN) + n;
    const float* ga = gamma + n;
    const double* me = mean_arr + n;
    const double* is = invstd_arr + n;

    for (int t = 0; t < TT; ++t) {
        const double psp = (double)p[t * NN] + bb;
        const double bn  = (double)ga[t * NN] * (psp - me[t * NN]) * is[t * NN];
        v = v * dv + bn - r;
        const double s = (v > 1.0) ? 1.0 : 0.0;
        r = r * rd + s * rv;
        spk[tid * (TT + 1) + t] = (float)s;
    }
    __syncthreads();

    const size_t base = (size_t)b * (NN * TT) + (size_t)nc * (256 * TT);
    for (int i = tid; i < 256 * TT; i += 256) {
        const int n_l = i / TT;
        out[base + i] = spk[n_l * (TT + 1) + (i - n_l * TT)];
    }

    const size_t fin = (size_t)BATCH * NN * TT;
    out[fin + (size_t)b * NN + n]                      = (float)v;
    out[fin + (size_t)BATCH * NN + (size_t)b * NN + n] = (float)r;
}

// ---------------------------------------------------------------------------
template <typename PT>
static void launch_fp64(const float* X, const float* W, const float* bias,
                        const float* gamma, const float* decay_v,
                        const float* reset_dec, const float* reset_v,
                        float* out, void* d_ws, hipStream_t stream)
{
    PT* PSP = (PT*)d_ws;
    char* after = (char*)d_ws + (size_t)MM * NN * sizeof(PT);
    double* meanA  = (double*)after;
    double* invstd = meanA + (size_t)TT * NN;

    dim3 ggrid(NN / 64, MM / 64);
    gemm_psp_kernel<PT><<<ggrid, 256, 0, stream>>>(X, W, PSP);
    stats_kernel<PT><<<TT * (NN / 256), 256, 0, stream>>>(PSP, bias, meanA, invstd);
    recur_kernel<PT><<<BATCH * (NN / 256), 256, 0, stream>>>(
        PSP, bias, meanA, invstd, gamma, decay_v, reset_dec, reset_v, out);
}

extern "C" void kernel_launch(void* const* d_in, const int* in_sizes, int n_in,
                              void* d_out, int out_size, void* d_ws, size_t ws_size,
                              hipStream_t stream) {
    (void)in_sizes; (void)n_in; (void)out_size;
    const float* X          = (const float*)d_in[0];
    const float* W          = (const float*)d_in[1];
    const float* bias       = (const float*)d_in[2];
    const float* gamma      = (const float*)d_in[3];
    const float* decay_v    = (const float*)d_in[4];
    const float* reset_dec  = (const float*)d_in[5];
    const float* reset_v    = (const float*)d_in[6];
    float* out = (float*)d_out;

    const size_t psp_f   = (size_t)MM * NN * sizeof(float);    // 52.43 MB
    const size_t psp_d   = (size_t)MM * NN * sizeof(double);   // 104.86 MB
    const size_t stats_b = (size_t)TT * NN * 2 * sizeof(double);
    const size_t adig_b  = (size_t)NDIG * MM * DIN;            // 52.43 MB
    const size_t bdig_b  = (size_t)NDIG * NN * DIN;            // 16.78 MB
    const size_t need_i8 = psp_f + stats_b + adig_b + bdig_b + NN * sizeof(double);
    const size_t need_d  = psp_d + stats_b;

    if (ws_size >= need_i8) {
        float*  PSP    = (float*)d_ws;
        char*   cur    = (char*)d_ws + psp_f;
        double* meanA  = (double*)cur;              cur += (size_t)TT * NN * 8;
        double* invstd = (double*)cur;              cur += (size_t)TT * NN * 8;
        signed char* Adig = (signed char*)cur;      cur += adig_b;
        signed char* Bdig = (signed char*)cur;      cur += bdig_b;
        double* invB   = (double*)cur;

        split_a_kernel<<<dim3(BATCH, 8), 256, 0, stream>>>(X, Adig);
        split_b_kernel<<<NN / 4, 256, 0, stream>>>(W, Bdig, invB);
        gemm_i8_kernel<<<dim3((MM / 128) * (NN / 64)), 256, 0, stream>>>(
            Adig, Bdig, invB, PSP);
        stats_kernel<float><<<TT * (NN / 256), 256, 0, stream>>>(PSP, bias, meanA, invstd);
        recur_kernel<float><<<BATCH * (NN / 256), 256, 0, stream>>>(
            PSP, bias, meanA, invstd, gamma, decay_v, reset_dec, reset_v, out);
    } else if (ws_size >= need_d) {
        launch_fp64<double>(X, W, bias, gamma, decay_v, reset_dec, reset_v, out, d_ws, stream);
    } else {
        launch_fp64<float>(X, W, bias, gamma, decay_v, reset_dec, reset_v, out, d_ws, stream);
    }
}

// Round 11
// 460.344 us; speedup vs baseline: 1.4806x; 1.0438x over previous
//
#include <hip/hip_runtime.h>
#include <cstddef>
#include <math.h>

// Problem constants (from reference)
#define BATCH 128
#define DIN   2048
#define NN    2048
#define TT    50
#define MM    (BATCH * TT)   // 6400, m = b*50 + t
#define BN_EPS 1e-4
#define NDIG  4              // 4 digits, pairs i+j<=3 (10)

typedef double double4_t __attribute__((ext_vector_type(4)));
typedef int    int4v    __attribute__((ext_vector_type(4)));
typedef int    int16v   __attribute__((ext_vector_type(16)));

// XOR bank swizzle for the fp64 fallback GEMM
#define SWZ(x) (((x) & 7) << 2)

// ===========================================================================
// TIER 1: exact-enough int8-Ozaki GEMM (4 digits, 10 pairs, int32-exact).
//
// R11 changes (gemm untouched -- R10's 247us/53.9% MfmaUtil kept):
//  * split_a / split_b store digit planes as 16B int4 per digit per thread
//    (was 1-byte scattered stores: 52.4M + 16.8M byte-stores dominated the
//    233us non-gemm time vs its ~65us roofline).  The R10 tiled layout
//    makes 16 consecutive k's = one contiguous 16B span at row*16, so a
//    thread processing (t, 16-k-group) packs 4x int4 in registers and does
//    4 vector stores; consecutive t -> consecutive 16B slots (coalesced).
// Kept (counter-verified): R10 pre-tiled fragment-order planes (gemm 528->
// 247us, FETCH 237MB, WRITE 51MB no-spill, conflicts 0), 128x64 block tile
// wave=32x64, A dbuf + B single-buf 80KB, plain-__syncthreads skeleton,
// mfma_i32_32x32x32_i8, fixed A scale sA=64, f32 PSP, one-pass stats,
// XCD-aware grid.
// ===========================================================================

__device__ __forceinline__ void gload16(const void* g, void* l) {
    __builtin_amdgcn_global_load_lds(
        (const __attribute__((address_space(1))) void*)g,
        (__attribute__((address_space(3))) void*)l, 16, 0, 0);
}

// --- split A: X -> Adig tiled [p][mp][kc][ksub][row][16], scale 64 --------
// grid (BATCH, 8): each block handles a 256-wide k-slice of one batch row.
// Thread task = (t, 16-k group): 16 LDS reads -> 4 x int4 stores.
__global__ __launch_bounds__(256) void split_a_kernel(
    const float* __restrict__ X,
    signed char* __restrict__ Adig)
{
    __shared__ float Xs[64 * TT];     // 64k x 50t tile

    const int b  = blockIdx.x;
    const int gy = blockIdx.y;        // 8-way K split (each block: 256 k's)
    const int tid = threadIdx.x;
    const float* Xb = X + (size_t)b * (DIN * TT);

    for (int k0 = gy * (DIN / 8); k0 < (gy + 1) * (DIN / 8); k0 += 64) {
        for (int idx = tid; idx < 64 * TT; idx += 256)
            Xs[idx] = Xb[k0 * TT + idx];      // flat-coalesced
        __syncthreads();
        // tasks: kg in [0,4) (16-k groups), t in [0,TT): 200 tasks
        for (int idx = tid; idx < 4 * TT; idx += 256) {
            const int t   = idx % TT;
            const int kg  = idx / TT;
            const int kl16 = kg << 4;
            const int mrow = b * TT + t;
            const int mp  = mrow >> 5;
            const int row = mrow & 31;
            const int kcl = (k0 + kl16) >> 5;
            const int sub = ((kl16 >> 4) & 1) << 9;

            signed char dig[NDIG][16];
#pragma unroll
            for (int j = 0; j < 16; ++j) {
                float r = Xs[(kl16 + j) * TT + t] * 64.f;   // fixed sA = 2^6
#pragma unroll
                for (int i = 0; i < NDIG; ++i) {
                    float di = rintf(r);
                    r = (r - di) * 128.f;         // exact in fp32
                    dig[i][j] = (signed char)(int)di;  // |di| <= 64
                }
            }
#pragma unroll
            for (int i = 0; i < NDIG; ++i)
                *(int4*)&Adig[((((size_t)i * (MM / 32) + mp) * (DIN / 32) + kcl)
                               << 10) + sub + (row << 4)] = *(const int4*)dig[i];
        }
        __syncthreads();
    }
}

// --- split B: W -> Bdig tiled [p][np][kc][ksub][row][16] + invB[N] ---------
// Thread task = 16-k group: 16 contiguous global reads -> 4 x int4 stores.
__global__ __launch_bounds__(256) void split_b_kernel(
    const float* __restrict__ W,
    signed char* __restrict__ Bdig,
    double* __restrict__ invB)
{
    __shared__ float red[256];
    __shared__ float sBsh;
    const int tid = threadIdx.x;
    for (int rep = 0; rep < 4; ++rep) {
        const int n = blockIdx.x * 4 + rep;
        const float* Wr = W + (size_t)n * DIN;
        float m_loc = 0.f;
        for (int k = tid; k < DIN; k += 256)
            m_loc = fmaxf(m_loc, fabsf(Wr[k]));
        red[tid] = m_loc;
        __syncthreads();
        for (int s = 128; s > 0; s >>= 1) {
            if (tid < s) red[tid] = fmaxf(red[tid], red[tid + s]);
            __syncthreads();
        }
        if (tid == 0) {
            float m = (red[0] == 0.f) ? 1.f : red[0];
            int ex; frexpf(m, &ex);
            sBsh = exp2f((float)(6 - ex));
            invB[n] = ldexp(1.0, ex - 6);
        }
        __syncthreads();
        const float sB = sBsh;
        const int np   = n >> 5;
        const int rowb = (n & 31) << 4;
        for (int g = tid; g < DIN / 16; g += 256) {   // 128 groups of 16 k
            const int k16 = g << 4;
            const int kc  = k16 >> 5;
            const int sub = ((k16 >> 4) & 1) << 9;
            signed char dig[NDIG][16];
#pragma unroll
            for (int j = 0; j < 16; ++j) {
                float r = Wr[k16 + j] * sB;
#pragma unroll
                for (int i = 0; i < NDIG; ++i) {
                    float di = rintf(r);
                    r = (r - di) * 128.f;
                    dig[i][j] = (signed char)(int)di;
                }
            }
#pragma unroll
            for (int i = 0; i < NDIG; ++i)
                *(int4*)&Bdig[((((size_t)i * (NN / 32) + np) * (DIN / 32) + kc)
                               << 10) + sub + rowb] = *(const int4*)dig[i];
        }
        __syncthreads();
    }
}

// --- i8 GEMM: 128x64 block tile, 4 waves (each 32x64), K-tile 64 -----------
// A dbuf (64 KB) + B single-buf (16 KB) = 80 KB, 2 blocks/CU.  (R10, kept)
#define PAIRS(NH, BARR)                                                    \
    __builtin_amdgcn_s_setprio(1);                                         \
    _Pragma("unroll")                                                      \
    for (int kc = 0; kc < 2; ++kc)                                         \
        _Pragma("unroll")                                                  \
        for (int i = 0; i < NDIG; ++i)                                     \
            _Pragma("unroll")                                              \
            for (int j = 0; j + i < NDIG; ++j)                             \
                acc[NH][i + j] = __builtin_amdgcn_mfma_i32_32x32x32_i8(    \
                    a[kc][i], BARR[kc][j], acc[NH][i + j], 0, 0, 0);       \
    __builtin_amdgcn_s_setprio(0);

#define TILE(BUF, IT)                                                      \
    {                                                                      \
        int4v a[2][NDIG], bb[2][NDIG];                                     \
        _Pragma("unroll")                                                  \
        for (int c = 0; c < 2; ++c)                                        \
            _Pragma("unroll")                                              \
            for (int p = 0; p < NDIG; ++p) {                               \
                a[c][p]  = *(const int4v*)&Asd[BUF][p][wv][c][lane << 4];  \
                bb[c][p] = *(const int4v*)&Bsd[p][0][c][lane << 4];        \
            }                                                              \
        PAIRS(0, bb)                                                       \
        _Pragma("unroll")                                                  \
        for (int c = 0; c < 2; ++c)                                        \
            _Pragma("unroll")                                              \
            for (int p = 0; p < NDIG; ++p)                                 \
                bb[c][p] = *(const int4v*)&Bsd[p][1][c][lane << 4];        \
        __syncthreads();                                                   \
        if ((IT) + 1 < NIT) { stageA((BUF) ^ 1, (IT) + 1); stageB((IT) + 1); } \
        __builtin_amdgcn_sched_barrier(0);                                 \
        PAIRS(1, bb)                                                       \
        __syncthreads();                                                   \
    }

__global__ __launch_bounds__(256, 2) void gemm_i8_kernel(
    const signed char* __restrict__ Adig,   // [4][MM/32][DIN/32] 1KB frag blocks
    const signed char* __restrict__ Bdig,   // [4][NN/32][DIN/32] 1KB frag blocks
    const double* __restrict__ invB,        // [NN]
    float* __restrict__ PSP)                // [MM][NN] (f32)
{
    // Asd[buf][digit][panel][kc][1KB], Bsd[digit][nh][kc][1KB]
    __shared__ __align__(16) signed char Asd[2][NDIG][4][2][1024];  // 64 KB
    __shared__ __align__(16) signed char Bsd[NDIG][2][2][1024];     // 16 KB

    const int tid  = threadIdx.x;
    const int lane = tid & 63;
    const int wv   = tid >> 6;

    // XCD-aware decomposition (1600 blocks, %8==0): xcd = bid&7 owns 4
    // n-strips (B 2MB, L2-resident); 4 consecutive blocks share one A panel.
    const int orig  = blockIdx.x;            // 0..1599
    const int local = orig >> 3;             // 0..199
    const int n0 = (((orig & 7) << 2) + (local & 3)) << 6;
    const int m0 = (local >> 2) << 7;        // 128-row panels

    const int mpw = (m0 >> 5) + wv;          // wave's own A 32-row panel
    const int np0 = n0 >> 5;
    const int bnh = wv & 1, bkc = wv >> 1;   // B staging assignment
    const size_t APL = ((size_t)(MM / 32) * (DIN / 32)) << 10;  // digit stride
    const size_t BPL = ((size_t)(NN / 32) * (DIN / 32)) << 10;
    const signed char* Abase =
        Adig + (((size_t)mpw * (DIN / 32)) << 10) + (lane << 4);
    const signed char* Bbase =
        Bdig + (((size_t)(np0 + bnh) * (DIN / 32)) << 10) + (lane << 4);

    auto stageA = [&](int buf, int kt) {
#pragma unroll
        for (int p = 0; p < NDIG; ++p)
#pragma unroll
            for (int c = 0; c < 2; ++c)
                gload16(Abase + (size_t)p * APL + ((size_t)((kt << 1) + c) << 10),
                        &Asd[buf][p][wv][c][0]);
    };
    auto stageB = [&](int kt) {
#pragma unroll
        for (int p = 0; p < NDIG; ++p)
            gload16(Bbase + (size_t)p * BPL + ((size_t)((kt << 1) + bkc) << 10),
                    &Bsd[p][bnh][bkc][0]);
    };

    int16v acc[2][NDIG];
#pragma unroll
    for (int nh = 0; nh < 2; ++nh)
#pragma unroll
        for (int w = 0; w < NDIG; ++w)
#pragma unroll
            for (int e = 0; e < 16; ++e) acc[nh][w][e] = 0;

    // prologue: stage tile 0 (A buf0 + B), drain, go
    stageA(0, 0);
    stageB(0);
    __syncthreads();

    const int NIT = DIN / 64;                // 32, even
    for (int it = 0; it < NIT; it += 2) {
        TILE(0, it);
        TILE(1, it + 1);
    }

    // epilogue: D layout col=lane&31, row=(reg&3)+8*(reg>>2)+4*(lane>>5)
    const double c1 = 1.0 / 128.0, c2 = c1 * c1, c3 = c2 * c1;
    const double invA = 1.0 / 64.0;          // fixed A scale
    const int colr  = lane & 31;
    const int rbase = m0 + (wv << 5) + 4 * (lane >> 5);
#pragma unroll
    for (int nh = 0; nh < 2; ++nh) {
        const int ncol = n0 + (nh << 5) + colr;
        const double ib = invA * invB[ncol];
#pragma unroll
        for (int reg = 0; reg < 16; ++reg) {
            const int mrow = rbase + (reg & 3) + 8 * (reg >> 2);
            double s = (double)acc[nh][0][reg]
                     + c1 * (double)acc[nh][1][reg]
                     + c2 * (double)acc[nh][2][reg]
                     + c3 * (double)acc[nh][3][reg];
            PSP[(size_t)mrow * NN + ncol] = (float)(s * ib);
        }
    }
}

// ===========================================================================
// TIER 2 fallback: fp64-MFMA GEMM (round-8, proven 1039 us total)
// ===========================================================================
#define BKK 32

template <typename PT>
__global__ __launch_bounds__(256, 5) void gemm_psp_kernel(
    const float* __restrict__ X,
    const float* __restrict__ W,
    PT* __restrict__ PSP)
{
    __shared__ float As[2][BKK][64];
    __shared__ float Bs[2][64][BKK];

    const int tid = threadIdx.x;
    const int m0 = blockIdx.y * 64;
    const int n0 = blockIdx.x * 64;

    const int a_m = tid & 63;
    const int a_k = tid >> 6;
    const int m_g = m0 + a_m;
    const int ab  = m_g / TT;
    const int at  = m_g - ab * TT;
    const float* Aptr = X + (size_t)ab * (DIN * TT) + at;

    const int b_n = tid >> 2;
    const int b_k = (tid & 3) * 8;
    const float* Wptr = W + (size_t)(n0 + b_n) * DIN + b_k;
    const int bswz_st = SWZ(b_n);

    const int lane = tid & 63;
    const int wv   = tid >> 6;
    const int wm   = (wv >> 1) * 32;
    const int wn   = (wv & 1) * 32;
    const int row  = lane & 15;
    const int grp  = lane >> 4;
    const int bswz_rd = SWZ(row);

    double4_t acc[2][2];
#pragma unroll
    for (int i = 0; i < 2; ++i)
#pragma unroll
        for (int j = 0; j < 2; ++j) acc[i][j] = double4_t{0.0, 0.0, 0.0, 0.0};

    {
#pragma unroll
        for (int j = 0; j < 8; ++j) {
            const int kr = a_k + 4 * j;
            As[0][kr][a_m ^ SWZ(kr)] = Aptr[kr * TT];
        }
        *(float4*)&Bs[0][b_n][(b_k + 0) ^ bswz_st] = *(const float4*)(Wptr);
        *(float4*)&Bs[0][b_n][(b_k + 4) ^ bswz_st] = *(const float4*)(Wptr + 4);
    }

    const int NIT = DIN / BKK;
    for (int it = 0; it < NIT; ++it) {
        const int buf = it & 1;
        __syncthreads();

        float a_nxt[8];
        float4 b_nxt0, b_nxt1;
        if (it + 1 < NIT) {
            const int k0n = (it + 1) * BKK;
#pragma unroll
            for (int j = 0; j < 8; ++j)
                a_nxt[j] = Aptr[(k0n + a_k + 4 * j) * TT];
            b_nxt0 = *(const float4*)(Wptr + k0n);
            b_nxt1 = *(const float4*)(Wptr + k0n + 4);
        }

#pragma unroll
        for (int kq = 0; kq < BKK; kq += 4) {
            const int kr = kq + grp;
            const int aswz = SWZ(kr);
            const double a0 = (double)As[buf][kr][(wm + row) ^ aswz];
            const double a1 = (double)As[buf][kr][(wm + row + 16) ^ aswz];
            const double b0 = (double)Bs[buf][wn + row][kr ^ bswz_rd];
            const double b1 = (double)Bs[buf][wn + row + 16][kr ^ bswz_rd];
            acc[0][0] = __builtin_amdgcn_mfma_f64_16x16x4f64(a0, b0, acc[0][0], 0, 0, 0);
            acc[0][1] = __builtin_amdgcn_mfma_f64_16x16x4f64(a0, b1, acc[0][1], 0, 0, 0);
            acc[1][0] = __builtin_amdgcn_mfma_f64_16x16x4f64(a1, b0, acc[1][0], 0, 0, 0);
            acc[1][1] = __builtin_amdgcn_mfma_f64_16x16x4f64(a1, b1, acc[1][1], 0, 0, 0);
        }

        if (it + 1 < NIT) {
            const int nb = 1 - buf;
#pragma unroll
            for (int j = 0; j < 8; ++j) {
                const int kr = a_k + 4 * j;
                As[nb][kr][a_m ^ SWZ(kr)] = a_nxt[j];
            }
            *(float4*)&Bs[nb][b_n][(b_k + 0) ^ bswz_st] = b_nxt0;
            *(float4*)&Bs[nb][b_n][(b_k + 4) ^ bswz_st] = b_nxt1;
        }
    }

#pragma unroll
    for (int i = 0; i < 2; ++i)
#pragma unroll
        for (int j = 0; j < 2; ++j)
#pragma unroll
            for (int r = 0; r < 4; ++r) {
                const int mrow = m0 + wm + 16 * i + grp + 4 * r;   // f64 H2 layout
                PSP[(size_t)mrow * NN + (n0 + wn + 16 * j + row)] = (PT)acc[i][j][r];
            }
}

// ---------------------------------------------------------------------------
// BN stats + LIF recurrence (shared by all tiers)
// ---------------------------------------------------------------------------
template <typename PT>
__global__ __launch_bounds__(256) void stats_kernel(
    const PT* __restrict__ PSP, const float* __restrict__ bias,
    double* __restrict__ mean_out, double* __restrict__ invstd_out)
{
    const int t = blockIdx.x >> 3;
    const int n = ((blockIdx.x & 7) << 8) + threadIdx.x;
    const double bb = (double)bias[n];
    const PT* p = PSP + (size_t)t * NN + n;

    // one-pass sum + sumsq (var = E[x^2]-E[x]^2, exact to ~1e-15 in double)
    double s = 0.0, ss = 0.0;
#pragma unroll 8
    for (int b = 0; b < BATCH; ++b) {
        const double v = (double)p[(size_t)b * (TT * NN)];
        s += v; ss += v * v;
    }
    const double mu0 = s * (1.0 / BATCH);
    const double var = fmax(ss * (1.0 / BATCH) - mu0 * mu0, 0.0);
    mean_out[t * NN + n]   = mu0 + bb;
    invstd_out[t * NN + n] = 1.0 / sqrt(var + BN_EPS);
}

template <typename PT>
__global__ __launch_bounds__(256) void recur_kernel(
    const PT* __restrict__ PSP, const float* __restrict__ bias,
    const double* __restrict__ mean_arr, const double* __restrict__ invstd_arr,
    const float* __restrict__ gamma, const float* __restrict__ decay_v,
    const float* __restrict__ reset_decay, const float* __restrict__ reset_v,
    float* __restrict__ out)
{
    __shared__ float spk[256 * (TT + 1)];

    const int b  = blockIdx.x >> 3;
    const int nc = blockIdx.x & 7;
    const int n  = (nc << 8) + threadIdx.x;
    const int tid = threadIdx.x;

    const double dv = (double)decay_v[n];
    const double rd = (double)reset_decay[n];
    const double rv = (double)reset_v[n];
    const double bb = (double)bias[n];

    double v = 0.0, r = 0.0;
    const PT* p = PSP + (size_t)b * (TT * NN) + n;
    const float* ga = gamma + n;
    const double* me = mean_arr + n;
    const double* is = invstd_arr + n;

    for (int t = 0; t < TT; ++t) {
        const double psp = (double)p[t * NN] + bb;
        const double bn  = (double)ga[t * NN] * (psp - me[t * NN]) * is[t * NN];
        v = v * dv + bn - r;
        const double s = (v > 1.0) ? 1.0 : 0.0;
        r = r * rd + s * rv;
        spk[tid * (TT + 1) + t] = (float)s;
    }
    __syncthreads();

    const size_t base = (size_t)b * (NN * TT) + (size_t)nc * (256 * TT);
    for (int i = tid; i < 256 * TT; i += 256) {
        const int n_l = i / TT;
        out[base + i] = spk[n_l * (TT + 1) + (i - n_l * TT)];
    }

    const size_t fin = (size_t)BATCH * NN * TT;
    out[fin + (size_t)b * NN + n]                      = (float)v;
    out[fin + (size_t)BATCH * NN + (size_t)b * NN + n] = (float)r;
}

// ---------------------------------------------------------------------------
template <typename PT>
static void launch_fp64(const float* X, const float* W, const float* bias,
                        const float* gamma, const float* decay_v,
                        const float* reset_dec, const float* reset_v,
                        float* out, void* d_ws, hipStream_t stream)
{
    PT* PSP = (PT*)d_ws;
    char* after = (char*)d_ws + (size_t)MM * NN * sizeof(PT);
    double* meanA  = (double*)after;
    double* invstd = meanA + (size_t)TT * NN;

    dim3 ggrid(NN / 64, MM / 64);
    gemm_psp_kernel<PT><<<ggrid, 256, 0, stream>>>(X, W, PSP);
    stats_kernel<PT><<<TT * (NN / 256), 256, 0, stream>>>(PSP, bias, meanA, invstd);
    recur_kernel<PT><<<BATCH * (NN / 256), 256, 0, stream>>>(
        PSP, bias, meanA, invstd, gamma, decay_v, reset_dec, reset_v, out);
}

extern "C" void kernel_launch(void* const* d_in, const int* in_sizes, int n_in,
                              void* d_out, int out_size, void* d_ws, size_t ws_size,
                              hipStream_t stream) {
    (void)in_sizes; (void)n_in; (void)out_size;
    const float* X          = (const float*)d_in[0];
    const float* W          = (const float*)d_in[1];
    const float* bias       = (const float*)d_in[2];
    const float* gamma      = (const float*)d_in[3];
    const float* decay_v    = (const float*)d_in[4];
    const float* reset_dec  = (const float*)d_in[5];
    const float* reset_v    = (const float*)d_in[6];
    float* out = (float*)d_out;

    const size_t psp_f   = (size_t)MM * NN * sizeof(float);    // 52.43 MB
    const size_t psp_d   = (size_t)MM * NN * sizeof(double);   // 104.86 MB
    const size_t stats_b = (size_t)TT * NN * 2 * sizeof(double);
    const size_t adig_b  = (size_t)NDIG * MM * DIN;            // 52.43 MB
    const size_t bdig_b  = (size_t)NDIG * NN * DIN;            // 16.78 MB
    const size_t need_i8 = psp_f + stats_b + adig_b + bdig_b + NN * sizeof(double);
    const size_t need_d  = psp_d + stats_b;

    if (ws_size >= need_i8) {
        float*  PSP    = (float*)d_ws;
        char*   cur    = (char*)d_ws + psp_f;
        double* meanA  = (double*)cur;              cur += (size_t)TT * NN * 8;
        double* invstd = (double*)cur;              cur += (size_t)TT * NN * 8;
        signed char* Adig = (signed char*)cur;      cur += adig_b;
        signed char* Bdig = (signed char*)cur;      cur += bdig_b;
        double* invB   = (double*)cur;

        split_a_kernel<<<dim3(BATCH, 8), 256, 0, stream>>>(X, Adig);
        split_b_kernel<<<NN / 4, 256, 0, stream>>>(W, Bdig, invB);
        gemm_i8_kernel<<<dim3((MM / 128) * (NN / 64)), 256, 0, stream>>>(
            Adig, Bdig, invB, PSP);
        stats_kernel<float><<<TT * (NN / 256), 256, 0, stream>>>(PSP, bias, meanA, invstd);
        recur_kernel<float><<<BATCH * (NN / 256), 256, 0, stream>>>(
            PSP, bias, meanA, invstd, gamma, decay_v, reset_dec, reset_v, out);
    } else if (ws_size >= need_d) {
        launch_fp64<double>(X, W, bias, gamma, decay_v, reset_dec, reset_v, out, d_ws, stream);
    } else {
        launch_fp64<float>(X, W, bias, gamma, decay_v, reset_dec, reset_v, out, d_ws, stream);
    }
}

// Round 12
// 440.972 us; speedup vs baseline: 1.5456x; 1.0439x over previous
//
#include <hip/hip_runtime.h>
#include <cstddef>
#include <math.h>

// Problem constants (from reference)
#define BATCH 128
#define DIN   2048
#define NN    2048
#define TT    50
#define MM    (BATCH * TT)   // 6400, m = b*50 + t
#define BN_EPS 1e-4
#define NDIG  4              // 4 digits, pairs i+j<=3 (10)

typedef double double4_t __attribute__((ext_vector_type(4)));
typedef int    int4v    __attribute__((ext_vector_type(4)));
typedef int    int16v   __attribute__((ext_vector_type(16)));

// XOR bank swizzle for the fp64 fallback GEMM
#define SWZ(x) (((x) & 7) << 2)

// ===========================================================================
// TIER 1: exact-enough int8-Ozaki GEMM (4 digits, 10 pairs, int32-exact).
//
// R12 changes (arithmetic untouched -> absmax must stay 0.015625):
//  * gemm: PERSISTENT grid of exactly 512 blocks (2/CU).  R10/R11's 1600
//    blocks over 512 slots = 3.125 fill-waves; the 512->0 drain ran ~75us
//    at ~50% util (~40us lost; Occupancy 18.8 vs 25 structural).  Each
//    block walks its XCD's tile queue ti = slot+64j over 200 tiles,
//    ordered so one m-panel's 4 n-strips run on adjacent slots
//    simultaneously (preserves R10's L2 A-panel sharing).  Imbalance
//    <= 1 tile (~17us) vs ~40us drain.
//  * split_a + split_b fused into ONE 1536-block kernel (independent
//    outputs; split_b rides under split_a + one launch gap removed).
// Kept (counter-verified): R10 pre-tiled fragment-order planes (gemm
// 528->247us, FETCH 237MB, no spill, conflicts 0), 128x64 tile wave=32x64,
// A dbuf + B single-buf 80KB, plain-__syncthreads skeleton,
// mfma_i32_32x32x32_i8, R11 16B vector split stores, fixed A scale sA=64,
// f32 PSP, one-pass stats, XCD-aware decomposition.
// ===========================================================================

__device__ __forceinline__ void gload16(const void* g, void* l) {
    __builtin_amdgcn_global_load_lds(
        (const __attribute__((address_space(1))) void*)g,
        (__attribute__((address_space(3))) void*)l, 16, 0, 0);
}

// --- fused split: blocks [0,1024) = A, [1024,1536) = B --------------------
// A: X -> Adig tiled [p][mp][kc][ksub][row][16], fixed scale 64.
//    block (b = bid>>3, gy = bid&7) handles a 256-wide k-slice of batch b.
// B: W -> Bdig tiled [p][np][kc][ksub][row][16] + invB[N]; 4 rows/block.
__global__ __launch_bounds__(256) void split_ab_kernel(
    const float* __restrict__ X,
    const float* __restrict__ W,
    signed char* __restrict__ Adig,
    signed char* __restrict__ Bdig,
    double* __restrict__ invB)
{
    __shared__ float Xs[64 * TT];     // A-path: 64k x 50t tile (12.8 KB)
    __shared__ float red[256];        // B-path reduction
    __shared__ float sBsh;

    const int tid = threadIdx.x;

    if (blockIdx.x < 1024) {
        // ---------------- split A ----------------
        const int b  = blockIdx.x >> 3;
        const int gy = blockIdx.x & 7;    // 8-way K split (256 k's each)
        const float* Xb = X + (size_t)b * (DIN * TT);

        for (int k0 = gy * (DIN / 8); k0 < (gy + 1) * (DIN / 8); k0 += 64) {
            for (int idx = tid; idx < 64 * TT; idx += 256)
                Xs[idx] = Xb[k0 * TT + idx];      // flat-coalesced
            __syncthreads();
            // tasks: kg in [0,4) (16-k groups), t in [0,TT): 200 tasks
            for (int idx = tid; idx < 4 * TT; idx += 256) {
                const int t    = idx % TT;
                const int kg   = idx / TT;
                const int kl16 = kg << 4;
                const int mrow = b * TT + t;
                const int mp   = mrow >> 5;
                const int row  = mrow & 31;
                const int kcl  = (k0 + kl16) >> 5;
                const int sub  = ((kl16 >> 4) & 1) << 9;

                signed char dig[NDIG][16];
#pragma unroll
                for (int j = 0; j < 16; ++j) {
                    float r = Xs[(kl16 + j) * TT + t] * 64.f;   // sA = 2^6
#pragma unroll
                    for (int i = 0; i < NDIG; ++i) {
                        float di = rintf(r);
                        r = (r - di) * 128.f;         // exact in fp32
                        dig[i][j] = (signed char)(int)di;  // |di| <= 64
                    }
                }
#pragma unroll
                for (int i = 0; i < NDIG; ++i)
                    *(int4*)&Adig[((((size_t)i * (MM / 32) + mp) * (DIN / 32)
                                    + kcl) << 10) + sub + (row << 4)]
                        = *(const int4*)dig[i];
            }
            __syncthreads();
        }
    } else {
        // ---------------- split B ----------------
        const int nb = blockIdx.x - 1024;     // 0..511
        for (int rep = 0; rep < 4; ++rep) {
            const int n = nb * 4 + rep;
            const float* Wr = W + (size_t)n * DIN;
            float m_loc = 0.f;
            for (int k = tid; k < DIN; k += 256)
                m_loc = fmaxf(m_loc, fabsf(Wr[k]));
            red[tid] = m_loc;
            __syncthreads();
            for (int s = 128; s > 0; s >>= 1) {
                if (tid < s) red[tid] = fmaxf(red[tid], red[tid + s]);
                __syncthreads();
            }
            if (tid == 0) {
                float m = (red[0] == 0.f) ? 1.f : red[0];
                int ex; frexpf(m, &ex);
                sBsh = exp2f((float)(6 - ex));
                invB[n] = ldexp(1.0, ex - 6);
            }
            __syncthreads();
            const float sB = sBsh;
            const int np   = n >> 5;
            const int rowb = (n & 31) << 4;
            for (int g = tid; g < DIN / 16; g += 256) {   // 128 groups
                const int k16 = g << 4;
                const int kc  = k16 >> 5;
                const int sub = ((k16 >> 4) & 1) << 9;
                signed char dig[NDIG][16];
#pragma unroll
                for (int j = 0; j < 16; ++j) {
                    float r = Wr[k16 + j] * sB;
#pragma unroll
                    for (int i = 0; i < NDIG; ++i) {
                        float di = rintf(r);
                        r = (r - di) * 128.f;
                        dig[i][j] = (signed char)(int)di;
                    }
                }
#pragma unroll
                for (int i = 0; i < NDIG; ++i)
                    *(int4*)&Bdig[((((size_t)i * (NN / 32) + np) * (DIN / 32)
                                    + kc) << 10) + sub + rowb]
                        = *(const int4*)dig[i];
            }
            __syncthreads();
        }
    }
}

// --- i8 GEMM: 128x64 block tile, 4 waves (each 32x64), K-tile 64 -----------
// A dbuf (64 KB) + B single-buf (16 KB) = 80 KB, 2 blocks/CU.
// PERSISTENT: 512 blocks; block = (xcd = bid&7, slot = bid>>3) walks its
// XCD's 200-tile queue ti = slot + 64j (nsub = ti&3, mp = ti>>2).
#define PAIRS(NH, BARR)                                                    \
    __builtin_amdgcn_s_setprio(1);                                         \
    _Pragma("unroll")                                                      \
    for (int kc = 0; kc < 2; ++kc)                                         \
        _Pragma("unroll")                                                  \
        for (int i = 0; i < NDIG; ++i)                                     \
            _Pragma("unroll")                                              \
            for (int j = 0; j + i < NDIG; ++j)                             \
                acc[NH][i + j] = __builtin_amdgcn_mfma_i32_32x32x32_i8(    \
                    a[kc][i], BARR[kc][j], acc[NH][i + j], 0, 0, 0);       \
    __builtin_amdgcn_s_setprio(0);

#define TILE(BUF, IT)                                                      \
    {                                                                      \
        int4v a[2][NDIG], bb[2][NDIG];                                     \
        _Pragma("unroll")                                                  \
        for (int c = 0; c < 2; ++c)                                        \
            _Pragma("unroll")                                              \
            for (int p = 0; p < NDIG; ++p) {                               \
                a[c][p]  = *(const int4v*)&Asd[BUF][p][wv][c][lane << 4];  \
                bb[c][p] = *(const int4v*)&Bsd[p][0][c][lane << 4];        \
            }                                                              \
        PAIRS(0, bb)                                                       \
        _Pragma("unroll")                                                  \
        for (int c = 0; c < 2; ++c)                                        \
            _Pragma("unroll")                                              \
            for (int p = 0; p < NDIG; ++p)                                 \
                bb[c][p] = *(const int4v*)&Bsd[p][1][c][lane << 4];        \
        __syncthreads();                                                   \
        if ((IT) + 1 < NIT) { stageA((BUF) ^ 1, (IT) + 1); stageB((IT) + 1); } \
        __builtin_amdgcn_sched_barrier(0);                                 \
        PAIRS(1, bb)                                                       \
        __syncthreads();                                                   \
    }

__global__ __launch_bounds__(256, 2) void gemm_i8_kernel(
    const signed char* __restrict__ Adig,   // [4][MM/32][DIN/32] 1KB frag blocks
    const signed char* __restrict__ Bdig,   // [4][NN/32][DIN/32] 1KB frag blocks
    const double* __restrict__ invB,        // [NN]
    float* __restrict__ PSP)                // [MM][NN] (f32)
{
    // Asd[buf][digit][panel][kc][1KB], Bsd[digit][nh][kc][1KB]
    __shared__ __align__(16) signed char Asd[2][NDIG][4][2][1024];  // 64 KB
    __shared__ __align__(16) signed char Bsd[NDIG][2][2][1024];     // 16 KB

    const int tid  = threadIdx.x;
    const int lane = tid & 63;
    const int wv   = tid >> 6;

    const int xcd  = blockIdx.x & 7;         // owns n-strips [xcd*4, xcd*4+4)
    const int slot = blockIdx.x >> 3;        // 0..63

    const int bnh = wv & 1, bkc = wv >> 1;   // B staging assignment
    const size_t APL = ((size_t)(MM / 32) * (DIN / 32)) << 10;  // digit stride
    const size_t BPL = ((size_t)(NN / 32) * (DIN / 32)) << 10;
    const int NIT = DIN / 64;                // 32, even

    // tile queue: at round j, slots cover 16 consecutive m-panels x 4
    // n-strips -> adjacent slots share one A panel simultaneously (L2).
    for (int ti = slot; ti < 200; ti += 64) {
        const int n0 = ((xcd << 2) + (ti & 3)) << 6;
        const int m0 = (ti >> 2) << 7;       // 128-row panel

        const int mpw = (m0 >> 5) + wv;      // wave's own A 32-row panel
        const signed char* Abase =
            Adig + (((size_t)mpw * (DIN / 32)) << 10) + (lane << 4);
        const signed char* Bbase =
            Bdig + (((size_t)((n0 >> 5) + bnh) * (DIN / 32)) << 10) + (lane << 4);

        auto stageA = [&](int buf, int kt) {
#pragma unroll
            for (int p = 0; p < NDIG; ++p)
#pragma unroll
                for (int c = 0; c < 2; ++c)
                    gload16(Abase + (size_t)p * APL
                                  + ((size_t)((kt << 1) + c) << 10),
                            &Asd[buf][p][wv][c][0]);
        };
        auto stageB = [&](int kt) {
#pragma unroll
            for (int p = 0; p < NDIG; ++p)
                gload16(Bbase + (size_t)p * BPL
                              + ((size_t)((kt << 1) + bkc) << 10),
                        &Bsd[p][bnh][bkc][0]);
        };

        int16v acc[2][NDIG];
#pragma unroll
        for (int nh = 0; nh < 2; ++nh)
#pragma unroll
            for (int w = 0; w < NDIG; ++w)
#pragma unroll
                for (int e = 0; e < 16; ++e) acc[nh][w][e] = 0;

        // prologue: stage tile 0 (A buf0 + B), drain, go
        stageA(0, 0);
        stageB(0);
        __syncthreads();

        for (int it = 0; it < NIT; it += 2) {
            TILE(0, it);
            TILE(1, it + 1);
        }

        // epilogue: D layout col=lane&31, row=(reg&3)+8*(reg>>2)+4*(lane>>5)
        const double c1 = 1.0 / 128.0, c2 = c1 * c1, c3 = c2 * c1;
        const double invA = 1.0 / 64.0;      // fixed A scale
        const int colr  = lane & 31;
        const int rbase = m0 + (wv << 5) + 4 * (lane >> 5);
#pragma unroll
        for (int nh = 0; nh < 2; ++nh) {
            const int ncol = n0 + (nh << 5) + colr;
            const double ib = invA * invB[ncol];
#pragma unroll
            for (int reg = 0; reg < 16; ++reg) {
                const int mrow = rbase + (reg & 3) + 8 * (reg >> 2);
                double s = (double)acc[nh][0][reg]
                         + c1 * (double)acc[nh][1][reg]
                         + c2 * (double)acc[nh][2][reg]
                         + c3 * (double)acc[nh][3][reg];
                PSP[(size_t)mrow * NN + ncol] = (float)(s * ib);
            }
        }
        // last TILE's end __syncthreads already ordered all LDS reads
        // before the next iteration's staging writes.
    }
}

// ===========================================================================
// TIER 2 fallback: fp64-MFMA GEMM (round-8, proven 1039 us total)
// ===========================================================================
#define BKK 32

template <typename PT>
__global__ __launch_bounds__(256, 5) void gemm_psp_kernel(
    const float* __restrict__ X,
    const float* __restrict__ W,
    PT* __restrict__ PSP)
{
    __shared__ float As[2][BKK][64];
    __shared__ float Bs[2][64][BKK];

    const int tid = threadIdx.x;
    const int m0 = blockIdx.y * 64;
    const int n0 = blockIdx.x * 64;

    const int a_m = tid & 63;
    const int a_k = tid >> 6;
    const int m_g = m0 + a_m;
    const int ab  = m_g / TT;
    const int at  = m_g - ab * TT;
    const float* Aptr = X + (size_t)ab * (DIN * TT) + at;

    const int b_n = tid >> 2;
    const int b_k = (tid & 3) * 8;
    const float* Wptr = W + (size_t)(n0 + b_n) * DIN + b_k;
    const int bswz_st = SWZ(b_n);

    const int lane = tid & 63;
    const int wv   = tid >> 6;
    const int wm   = (wv >> 1) * 32;
    const int wn   = (wv & 1) * 32;
    const int row  = lane & 15;
    const int grp  = lane >> 4;
    const int bswz_rd = SWZ(row);

    double4_t acc[2][2];
#pragma unroll
    for (int i = 0; i < 2; ++i)
#pragma unroll
        for (int j = 0; j < 2; ++j) acc[i][j] = double4_t{0.0, 0.0, 0.0, 0.0};

    {
#pragma unroll
        for (int j = 0; j < 8; ++j) {
            const int kr = a_k + 4 * j;
            As[0][kr][a_m ^ SWZ(kr)] = Aptr[kr * TT];
        }
        *(float4*)&Bs[0][b_n][(b_k + 0) ^ bswz_st] = *(const float4*)(Wptr);
        *(float4*)&Bs[0][b_n][(b_k + 4) ^ bswz_st] = *(const float4*)(Wptr + 4);
    }

    const int NIT = DIN / BKK;
    for (int it = 0; it < NIT; ++it) {
        const int buf = it & 1;
        __syncthreads();

        float a_nxt[8];
        float4 b_nxt0, b_nxt1;
        if (it + 1 < NIT) {
            const int k0n = (it + 1) * BKK;
#pragma unroll
            for (int j = 0; j < 8; ++j)
                a_nxt[j] = Aptr[(k0n + a_k + 4 * j) * TT];
            b_nxt0 = *(const float4*)(Wptr + k0n);
            b_nxt1 = *(const float4*)(Wptr + k0n + 4);
        }

#pragma unroll
        for (int kq = 0; kq < BKK; kq += 4) {
            const int kr = kq + grp;
            const int aswz = SWZ(kr);
            const double a0 = (double)As[buf][kr][(wm + row) ^ aswz];
            const double a1 = (double)As[buf][kr][(wm + row + 16) ^ aswz];
            const double b0 = (double)Bs[buf][wn + row][kr ^ bswz_rd];
            const double b1 = (double)Bs[buf][wn + row + 16][kr ^ bswz_rd];
            acc[0][0] = __builtin_amdgcn_mfma_f64_16x16x4f64(a0, b0, acc[0][0], 0, 0, 0);
            acc[0][1] = __builtin_amdgcn_mfma_f64_16x16x4f64(a0, b1, acc[0][1], 0, 0, 0);
            acc[1][0] = __builtin_amdgcn_mfma_f64_16x16x4f64(a1, b0, acc[1][0], 0, 0, 0);
            acc[1][1] = __builtin_amdgcn_mfma_f64_16x16x4f64(a1, b1, acc[1][1], 0, 0, 0);
        }

        if (it + 1 < NIT) {
            const int nb = 1 - buf;
#pragma unroll
            for (int j = 0; j < 8; ++j) {
                const int kr = a_k + 4 * j;
                As[nb][kr][a_m ^ SWZ(kr)] = a_nxt[j];
            }
            *(float4*)&Bs[nb][b_n][(b_k + 0) ^ bswz_st] = b_nxt0;
            *(float4*)&Bs[nb][b_n][(b_k + 4) ^ bswz_st] = b_nxt1;
        }
    }

#pragma unroll
    for (int i = 0; i < 2; ++i)
#pragma unroll
        for (int j = 0; j < 2; ++j)
#pragma unroll
            for (int r = 0; r < 4; ++r) {
                const int mrow = m0 + wm + 16 * i + grp + 4 * r;   // f64 H2 layout
                PSP[(size_t)mrow * NN + (n0 + wn + 16 * j + row)] = (PT)acc[i][j][r];
            }
}

// ---------------------------------------------------------------------------
// BN stats + LIF recurrence (shared by all tiers)
// ---------------------------------------------------------------------------
template <typename PT>
__global__ __launch_bounds__(256) void stats_kernel(
    const PT* __restrict__ PSP, const float* __restrict__ bias,
    double* __restrict__ mean_out, double* __restrict__ invstd_out)
{
    const int t = blockIdx.x >> 3;
    const int n = ((blockIdx.x & 7) << 8) + threadIdx.x;
    const double bb = (double)bias[n];
    const PT* p = PSP + (size_t)t * NN + n;

    // one-pass sum + sumsq (var = E[x^2]-E[x]^2, exact to ~1e-15 in double)
    double s = 0.0, ss = 0.0;
#pragma unroll 8
    for (int b = 0; b < BATCH; ++b) {
        const double v = (double)p[(size_t)b * (TT * NN)];
        s += v; ss += v * v;
    }
    const double mu0 = s * (1.0 / BATCH);
    const double var = fmax(ss * (1.0 / BATCH) - mu0 * mu0, 0.0);
    mean_out[t * NN + n]   = mu0 + bb;
    invstd_out[t * NN + n] = 1.0 / sqrt(var + BN_EPS);
}

template <typename PT>
__global__ __launch_bounds__(256) void recur_kernel(
    const PT* __restrict__ PSP, const float* __restrict__ bias,
    const double* __restrict__ mean_arr, const double* __restrict__ invstd_arr,
    const float* __restrict__ gamma, const float* __restrict__ decay_v,
    const float* __restrict__ reset_decay, const float* __restrict__ reset_v,
    float* __restrict__ out)
{
    __shared__ float spk[256 * (TT + 1)];

    const int b  = blockIdx.x >> 3;
    const int nc = blockIdx.x & 7;
    const int n  = (nc << 8) + threadIdx.x;
    const int tid = threadIdx.x;

    const double dv = (double)decay_v[n];
    const double rd = (double)reset_decay[n];
    const double rv = (double)reset_v[n];
    const double bb = (double)bias[n];

    double v = 0.0, r = 0.0;
    const PT* p = PSP + (size_t)b * (TT * NN) + n;
    const float* ga = gamma + n;
    const double* me = mean_arr + n;
    const double* is = invstd_arr + n;

    for (int t = 0; t < TT; ++t) {
        const double psp = (double)p[t * NN] + bb;
        const double bn  = (double)ga[t * NN] * (psp - me[t * NN]) * is[t * NN];
        v = v * dv + bn - r;
        const double s = (v > 1.0) ? 1.0 : 0.0;
        r = r * rd + s * rv;
        spk[tid * (TT + 1) + t] = (float)s;
    }
    __syncthreads();

    const size_t base = (size_t)b * (NN * TT) + (size_t)nc * (256 * TT);
    for (int i = tid; i < 256 * TT; i += 256) {
        const int n_l = i / TT;
        out[base + i] = spk[n_l * (TT + 1) + (i - n_l * TT)];
    }

    const size_t fin = (size_t)BATCH * NN * TT;
    out[fin + (size_t)b * NN + n]                      = (float)v;
    out[fin + (size_t)BATCH * NN + (size_t)b * NN + n] = (float)r;
}

// ---------------------------------------------------------------------------
template <typename PT>
static void launch_fp64(const float* X, const float* W, const float* bias,
                        const float* gamma, const float* decay_v,
                        const float* reset_dec, const float* reset_v,
                        float* out, void* d_ws, hipStream_t stream)
{
    PT* PSP = (PT*)d_ws;
    char* after = (char*)d_ws + (size_t)MM * NN * sizeof(PT);
    double* meanA  = (double*)after;
    double* invstd = meanA + (size_t)TT * NN;

    dim3 ggrid(NN / 64, MM / 64);
    gemm_psp_kernel<PT><<<ggrid, 256, 0, stream>>>(X, W, PSP);
    stats_kernel<PT><<<TT * (NN / 256), 256, 0, stream>>>(PSP, bias, meanA, invstd);
    recur_kernel<PT><<<BATCH * (NN / 256), 256, 0, stream>>>(
        PSP, bias, meanA, invstd, gamma, decay_v, reset_dec, reset_v, out);
}

extern "C" void kernel_launch(void* const* d_in, const int* in_sizes, int n_in,
                              void* d_out, int out_size, void* d_ws, size_t ws_size,
                              hipStream_t stream) {
    (void)in_sizes; (void)n_in; (void)out_size;
    const float* X          = (const float*)d_in[0];
    const float* W          = (const float*)d_in[1];
    const float* bias       = (const float*)d_in[2];
    const float* gamma      = (const float*)d_in[3];
    const float* decay_v    = (const float*)d_in[4];
    const float* reset_dec  = (const float*)d_in[5];
    const float* reset_v    = (const float*)d_in[6];
    float* out = (float*)d_out;

    const size_t psp_f   = (size_t)MM * NN * sizeof(float);    // 52.43 MB
    const size_t psp_d   = (size_t)MM * NN * sizeof(double);   // 104.86 MB
    const size_t stats_b = (size_t)TT * NN * 2 * sizeof(double);
    const size_t adig_b  = (size_t)NDIG * MM * DIN;            // 52.43 MB
    const size_t bdig_b  = (size_t)NDIG * NN * DIN;            // 16.78 MB
    const size_t need_i8 = psp_f + stats_b + adig_b + bdig_b + NN * sizeof(double);
    const size_t need_d  = psp_d + stats_b;

    if (ws_size >= need_i8) {
        float*  PSP    = (float*)d_ws;
        char*   cur    = (char*)d_ws + psp_f;
        double* meanA  = (double*)cur;              cur += (size_t)TT * NN * 8;
        double* invstd = (double*)cur;              cur += (size_t)TT * NN * 8;
        signed char* Adig = (signed char*)cur;      cur += adig_b;
        signed char* Bdig = (signed char*)cur;      cur += bdig_b;
        double* invB   = (double*)cur;

        split_ab_kernel<<<1536, 256, 0, stream>>>(X, W, Adig, Bdig, invB);
        gemm_i8_kernel<<<512, 256, 0, stream>>>(Adig, Bdig, invB, PSP);
        stats_kernel<float><<<TT * (NN / 256), 256, 0, stream>>>(PSP, bias, meanA, invstd);
        recur_kernel<float><<<BATCH * (NN / 256), 256, 0, stream>>>(
            PSP, bias, meanA, invstd, gamma, decay_v, reset_dec, reset_v, out);
    } else if (ws_size >= need_d) {
        launch_fp64<double>(X, W, bias, gamma, decay_v, reset_dec, reset_v, out, d_ws, stream);
    } else {
        launch_fp64<float>(X, W, bias, gamma, decay_v, reset_dec, reset_v, out, d_ws, stream);
    }
}